// Round 1
// baseline (756.168 us; speedup 1.0000x reference)
//
#include <hip/hip_runtime.h>
#include <math.h>

#define N_NODES 50000
#define N_EDGES 600000
#define D 128
#define EPS 1e-12f

#define SCAN_B 256
#define N_SCAN_BLOCKS ((N_NODES + SCAN_B - 1) / SCAN_B)   // 196

// ---------------- K0: normalize question embedding (1 block, 128 threads) ---
__global__ void qnorm_kernel(const float* __restrict__ q, float* __restrict__ qn) {
    __shared__ float red[2];
    int t = threadIdx.x;
    float v = q[t];
    float ss = v * v;
    #pragma unroll
    for (int off = 32; off > 0; off >>= 1) ss += __shfl_down(ss, off);
    if ((t & 63) == 0) red[t >> 6] = ss;
    __syncthreads();
    float inv = 1.0f / fmaxf(sqrtf(red[0] + red[1]), EPS);
    qn[t] = v * inv;
}

// ---------------- K1: edge cosine sim + degree count ------------------------
// two edges per wave: lanes 0-31 edge 2w, lanes 32-63 edge 2w+1, float4/lane.
__global__ void edge_sim_kernel(const float* __restrict__ ea,
                                const float* __restrict__ qn,
                                const int* __restrict__ dst,
                                float* __restrict__ sim,
                                int* __restrict__ cnt) {
    int gid  = blockIdx.x * blockDim.x + threadIdx.x;
    int wave = gid >> 6;
    if (wave >= N_EDGES / 2) return;
    int lane = threadIdx.x & 63;
    int half = lane >> 5;
    int l32  = lane & 31;
    int e    = 2 * wave + half;

    float4 v = ((const float4*)(ea + (size_t)e * D))[l32];
    float4 q = ((const float4*)qn)[l32];
    float dot = v.x * q.x + v.y * q.y + v.z * q.z + v.w * q.w;
    float ss  = v.x * v.x + v.y * v.y + v.z * v.z + v.w * v.w;
    // reduce within each 32-lane half (xor offsets < 32 never cross halves)
    #pragma unroll
    for (int off = 16; off > 0; off >>= 1) {
        dot += __shfl_xor(dot, off);
        ss  += __shfl_xor(ss, off);
    }
    if (l32 == 0) {
        sim[e] = dot / fmaxf(sqrtf(ss), EPS);
        atomicAdd(&cnt[dst[e]], 1);
    }
}

// ---------------- K2: 3-phase exclusive scan of cnt -> row_ptr ---------------
__global__ void block_sum_kernel(const int* __restrict__ cnt, int* __restrict__ bsum) {
    __shared__ int s[SCAN_B];
    int t = threadIdx.x;
    int i = blockIdx.x * SCAN_B + t;
    s[t] = (i < N_NODES) ? cnt[i] : 0;
    __syncthreads();
    for (int off = SCAN_B / 2; off > 0; off >>= 1) {
        if (t < off) s[t] += s[t + off];
        __syncthreads();
    }
    if (t == 0) bsum[blockIdx.x] = s[0];
}

__global__ void scan_bsums_kernel(int* __restrict__ bsum) {
    __shared__ int s[SCAN_B];
    int t = threadIdx.x;
    int v = (t < N_SCAN_BLOCKS) ? bsum[t] : 0;
    s[t] = v;
    __syncthreads();
    for (int off = 1; off < SCAN_B; off <<= 1) {
        int a = (t >= off) ? s[t - off] : 0;
        __syncthreads();
        s[t] += a;
        __syncthreads();
    }
    if (t < N_SCAN_BLOCKS) bsum[t] = s[t] - v;   // exclusive
}

// also emits deg_inv and cursor (saves two dispatches)
__global__ void scan_final_kernel(const int* __restrict__ cnt,
                                  const int* __restrict__ bsum,
                                  int* __restrict__ row_ptr,
                                  int* __restrict__ cursor,
                                  float* __restrict__ deg_inv) {
    __shared__ int s[SCAN_B];
    int t = threadIdx.x;
    int i = blockIdx.x * SCAN_B + t;
    int v = (i < N_NODES) ? cnt[i] : 0;
    s[t] = v;
    __syncthreads();
    for (int off = 1; off < SCAN_B; off <<= 1) {
        int a = (t >= off) ? s[t - off] : 0;
        __syncthreads();
        s[t] += a;
        __syncthreads();
    }
    if (i < N_NODES) {
        int rp = s[t] - v + bsum[blockIdx.x];
        row_ptr[i] = rp;
        cursor[i]  = rp;
        deg_inv[i] = 1.0f / fmaxf((float)v, 1.0f);
    }
    if (i == N_NODES - 1) row_ptr[N_NODES] = N_EDGES;
}

// ---------------- K3: fill CSR (src id + sim per incoming edge) -------------
__global__ void fill_kernel(const int* __restrict__ src, const int* __restrict__ dst,
                            const float* __restrict__ sim,
                            int* __restrict__ cursor,
                            int* __restrict__ csr_src, float* __restrict__ csr_sim) {
    int e = blockIdx.x * blockDim.x + threadIdx.x;
    if (e >= N_EDGES) return;
    int d = dst[e];
    int idx = atomicAdd(&cursor[d], 1);
    csr_src[idx] = src[e];
    csr_sim[idx] = sim[e];
}

// ---------------- K4: XCD-pinned chunked gather-aggregate -------------------
// D=128 split into 8 chunks of 16 floats (64 B = 1 cache line / edge / chunk).
// chunk = blockIdx.x & 7 -> pinned to one XCD by round-robin dispatch, so each
// XCD's gather working set is 50000*64B = 3.2 MB, fully resident in its 4 MB
// L2. One wave per (node, chunk); 4 edges processed in parallel by the four
// 16-lane groups. Output via non-temporal store so the written chunk doesn't
// evict the gather table from L2 (layer 2 re-reads it from L3/L2).
__global__ void agg_kernel(const float* __restrict__ xin,
                           const int* __restrict__ row_ptr,
                           const int* __restrict__ csr_src,
                           const float* __restrict__ csr_sim,
                           const float* __restrict__ deg_inv,
                           float* __restrict__ xout) {
    int bid   = blockIdx.x;
    int chunk = bid & 7;          // XCD-pinned feature chunk (16 floats)
    int group = bid >> 3;
    int wid   = threadIdx.x >> 6;
    int node  = group * 4 + wid;  // 4 waves/block, one node each
    if (node >= N_NODES) return;
    int lane = threadIdx.x & 63;
    int g    = lane >> 4;         // edge slot 0..3
    int l16  = lane & 15;

    int beg = row_ptr[node];
    int n   = row_ptr[node + 1] - beg;

    // preload up to 64 (src, sim) pairs into registers; pad with (node, 0)
    int   sl = node; float wl = 0.0f;
    int nc = (n < 64) ? n : 64;
    if (lane < nc) { sl = csr_src[beg + lane]; wl = csr_sim[beg + lane]; }

    const float* xc = xin + (size_t)chunk * 16 + l16;
    float acc = 0.0f;
    int nn4 = (nc + 3) & ~3;      // padded edge count (dummies have w=0)
    #pragma unroll 2
    for (int j = 0; j < nn4; j += 4) {
        int   s = __shfl(sl, j + g);
        float w = __shfl(wl, j + g);
        acc += xc[(size_t)s * D] * w;
    }
    // safety: degree > 64 (Poisson(12) — effectively never, but correct)
    for (int j = 64; j < n; j += 4) {
        int jj = j + g;
        int   s = (jj < n) ? csr_src[beg + jj] : node;
        float w = (jj < n) ? csr_sim[beg + jj] : 0.0f;
        acc += xc[(size_t)s * D] * w;
    }
    // combine the four 16-lane groups: lanes {l, l^16, l^32, l^48}
    acc += __shfl_xor(acc, 16);
    acc += __shfl_xor(acc, 32);

    if (lane < 16) {
        size_t o = (size_t)node * D + chunk * 16 + lane;
        float a  = xin[o];
        float r  = 0.5f * a + 0.5f * acc * deg_inv[node];
        __builtin_nontemporal_store(r, &xout[o]);
    }
}

extern "C" void kernel_launch(void* const* d_in, const int* in_sizes, int n_in,
                              void* d_out, int out_size, void* d_ws, size_t ws_size,
                              hipStream_t stream) {
    const float* x  = (const float*)d_in[0];   // [N, D]
    const float* ea = (const float*)d_in[1];   // [E, D]
    const float* q  = (const float*)d_in[2];   // [D]
    const int*   ei = (const int*)d_in[3];     // [2, E]
    const int* src = ei;
    const int* dst = ei + N_EDGES;
    float* out = (float*)d_out;                // [N, D]

    // ---- workspace layout (x1 first for 16B alignment) ----
    float* x1       = (float*)d_ws;                       // N*D floats
    float* sim      = x1 + (size_t)N_NODES * D;           // E
    float* csr_sim  = sim + N_EDGES;                      // E
    float* deg_inv  = csr_sim + N_EDGES;                  // N
    float* qn       = deg_inv + N_NODES;                  // 128
    int*   cnt      = (int*)(qn + 128);                   // N
    int*   row_ptr  = cnt + N_NODES;                      // N+1
    int*   cursor   = row_ptr + N_NODES + 1;              // N
    int*   bsum     = cursor + N_NODES;                   // 256
    int*   csr_src  = bsum + 256;                         // E

    hipMemsetAsync(cnt, 0, (size_t)N_NODES * sizeof(int), stream);

    qnorm_kernel<<<1, 128, 0, stream>>>(q, qn);

    {   // one wave per 2 edges
        long long threads = (long long)(N_EDGES / 2) * 64;
        int blocks = (int)((threads + 255) / 256);
        edge_sim_kernel<<<blocks, 256, 0, stream>>>(ea, qn, dst, sim, cnt);
    }

    block_sum_kernel<<<N_SCAN_BLOCKS, SCAN_B, 0, stream>>>(cnt, bsum);
    scan_bsums_kernel<<<1, SCAN_B, 0, stream>>>(bsum);
    scan_final_kernel<<<N_SCAN_BLOCKS, SCAN_B, 0, stream>>>(cnt, bsum, row_ptr, cursor, deg_inv);

    fill_kernel<<<(N_EDGES + 255) / 256, 256, 0, stream>>>(src, dst, sim, cursor, csr_src, csr_sim);

    // 8 chunk-blocks per node-group of 4; chunk = bid & 7 pins chunk -> XCD
    const int agg_blocks = (N_NODES / 4) * 8;   // 100000
    // layer 1: x -> x1 ; layer 2: x1 -> out (no in-place hazard)
    agg_kernel<<<agg_blocks, 256, 0, stream>>>(x,  row_ptr, csr_src, csr_sim, deg_inv, x1);
    agg_kernel<<<agg_blocks, 256, 0, stream>>>(x1, row_ptr, csr_src, csr_sim, deg_inv, out);
}

// Round 2
// 541.474 us; speedup vs baseline: 1.3965x; 1.3965x over previous
//
#include <hip/hip_runtime.h>
#include <math.h>

#define N_NODES 50000
#define N_EDGES 600000
#define D 128
#define EPS 1e-12f
#define CAP 64          // bucket slots per node; Poisson(12) => P(deg>64) ~ 1e-20,
                        // and the overflow path below keeps it correct regardless.

// ---------------- K1: fused edge cosine sim + bucket scatter ----------------
// two edges per wave: lanes 0-31 edge 2w, lanes 32-63 edge 2w+1, float4/lane.
// q-norm computed in-wave (3rd reduce chain) - no separate qnorm kernel.
// One atomic per edge claims a bucket slot; (src, sim) stored as int2.
__global__ void edge_fill_kernel(const float* __restrict__ ea,
                                 const float* __restrict__ q,
                                 const int* __restrict__ src,
                                 const int* __restrict__ dst,
                                 int* __restrict__ cnt,
                                 int2* __restrict__ bucket,
                                 int* __restrict__ ovf_cnt,
                                 int4* __restrict__ ovf) {
    int gid  = blockIdx.x * blockDim.x + threadIdx.x;
    int wave = gid >> 6;
    if (wave >= N_EDGES / 2) return;
    int lane = threadIdx.x & 63;
    int half = lane >> 5;
    int l32  = lane & 31;
    int e    = 2 * wave + half;

    float4 v  = ((const float4*)(ea + (size_t)e * D))[l32];
    float4 qv = ((const float4*)q)[l32];
    float dot = v.x * qv.x + v.y * qv.y + v.z * qv.z + v.w * qv.w;
    float ss  = v.x * v.x + v.y * v.y + v.z * v.z + v.w * v.w;
    float qs  = qv.x * qv.x + qv.y * qv.y + qv.z * qv.z + qv.w * qv.w;
    // reduce within each 32-lane half (xor offsets < 32 never cross halves)
    #pragma unroll
    for (int off = 16; off > 0; off >>= 1) {
        dot += __shfl_xor(dot, off);
        ss  += __shfl_xor(ss, off);
        qs  += __shfl_xor(qs, off);
    }
    if (l32 == 0) {
        float sim = dot / (fmaxf(sqrtf(ss), EPS) * fmaxf(sqrtf(qs), EPS));
        int d    = dst[e];
        int slot = atomicAdd(&cnt[d], 1);
        if (slot < CAP) {
            bucket[(size_t)d * CAP + slot] = make_int2(src[e], __float_as_int(sim));
        } else {
            int oi = atomicAdd(ovf_cnt, 1);
            ovf[oi] = make_int4(d, src[e], __float_as_int(sim), 0);
        }
    }
}

// ---------------- K2: fused gather-aggregate + mean + residual blend --------
// one wave per node (round-0 proven structure). Bucket entries preloaded into
// lane registers (one coalesced 512B int2 load), broadcast per-edge via shfl.
// Gather rows as float4 across 32 lanes; the two wave halves process even/odd
// edges concurrently. deg_inv computed inline from cnt.
__global__ void agg_kernel(const float* __restrict__ xin,
                           const int* __restrict__ cnt,
                           const int2* __restrict__ bucket,
                           float* __restrict__ xout) {
    int gid  = blockIdx.x * blockDim.x + threadIdx.x;
    int node = gid >> 6;
    if (node >= N_NODES) return;
    int lane = threadIdx.x & 63;
    int half = lane >> 5;
    int l32  = lane & 31;

    int n  = cnt[node];              // full degree (incl. any overflow edges)
    int nb = (n < CAP) ? n : CAP;    // edges present in the bucket

    // preload up to 64 (src, sim) pairs into registers - coalesced 512B
    int sl = 0; float wl = 0.0f;
    if (lane < nb) {
        int2 p = bucket[(size_t)node * CAP + lane];
        sl = p.x; wl = __int_as_float(p.y);
    }

    float4 acc = make_float4(0.0f, 0.0f, 0.0f, 0.0f);
    // halves interleave: half 0 takes even edges, half 1 odd
    #pragma unroll 2
    for (int j = half; j < nb; j += 2) {
        int   s = __shfl(sl, j);
        float w = __shfl(wl, j);
        float4 v = ((const float4*)(xin + (size_t)s * D))[l32];
        acc.x += v.x * w; acc.y += v.y * w; acc.z += v.z * w; acc.w += v.w * w;
    }
    // combine the two halves
    acc.x += __shfl_xor(acc.x, 32);
    acc.y += __shfl_xor(acc.y, 32);
    acc.z += __shfl_xor(acc.z, 32);
    acc.w += __shfl_xor(acc.w, 32);

    if (half == 0) {
        float di = 1.0f / fmaxf((float)n, 1.0f);
        float4 a = ((const float4*)(xin + (size_t)node * D))[l32];
        float4 o;
        o.x = 0.5f * a.x + 0.5f * acc.x * di;
        o.y = 0.5f * a.y + 0.5f * acc.y * di;
        o.z = 0.5f * a.z + 0.5f * acc.z * di;
        o.w = 0.5f * a.w + 0.5f * acc.w * di;
        ((float4*)(xout + (size_t)node * D))[l32] = o;
    }
}

// ---------------- K3: overflow fixup (degree > CAP) — empty in practice -----
// Serial over overflow entries (no races); adds the missing 0.5*w*di*x[src]
// contribution into xout. With Poisson(12) degrees this kernel sees m == 0
// and exits immediately; it exists so correctness never depends on CAP.
__global__ void ovf_fix_kernel(const float* __restrict__ xin,
                               const int* __restrict__ cnt,
                               const int* __restrict__ ovf_cnt,
                               const int4* __restrict__ ovf,
                               float* __restrict__ xout) {
    int t = threadIdx.x;             // 128 threads, 1 block
    int m = *ovf_cnt;
    for (int i = 0; i < m; ++i) {
        int4 p = ovf[i];
        int d = p.x, s = p.y;
        float w  = __int_as_float(p.z);
        float di = 1.0f / fmaxf((float)cnt[d], 1.0f);
        xout[(size_t)d * D + t] += 0.5f * w * di * xin[(size_t)s * D + t];
    }
}

extern "C" void kernel_launch(void* const* d_in, const int* in_sizes, int n_in,
                              void* d_out, int out_size, void* d_ws, size_t ws_size,
                              hipStream_t stream) {
    const float* x  = (const float*)d_in[0];   // [N, D]
    const float* ea = (const float*)d_in[1];   // [E, D]
    const float* q  = (const float*)d_in[2];   // [D]
    const int*   ei = (const int*)d_in[3];     // [2, E] (int32: jax x64 disabled)
    const int* src = ei;
    const int* dst = ei + N_EDGES;
    float* out = (float*)d_out;                // [N, D]

    // ---- workspace layout (16B-aligned pieces) ----
    float* x1      = (float*)d_ws;                         // N*D floats (25.6MB)
    int2*  bucket  = (int2*)(x1 + (size_t)N_NODES * D);    // N*CAP int2 (25.6MB)
    int*   cnt     = (int*)(bucket + (size_t)N_NODES * CAP); // N ints
    int*   ovf_cnt = cnt + N_NODES;                        // 1 int (+3 pad)
    int4*  ovf     = (int4*)(cnt + N_NODES + 4);           // 64K entries max

    // zero cnt + ovf_cnt in one memset (contiguous)
    hipMemsetAsync(cnt, 0, (size_t)(N_NODES + 4) * sizeof(int), stream);

    {   // one wave per 2 edges
        long long threads = (long long)(N_EDGES / 2) * 64;
        int blocks = (int)((threads + 255) / 256);
        edge_fill_kernel<<<blocks, 256, 0, stream>>>(ea, q, src, dst,
                                                     cnt, bucket, ovf_cnt, ovf);
    }

    const int agg_blocks = (int)(((long long)N_NODES * 64 + 255) / 256);
    // layer 1: x -> x1 ; layer 2: x1 -> out (no in-place hazard)
    agg_kernel<<<agg_blocks, 256, 0, stream>>>(x,  cnt, bucket, x1);
    ovf_fix_kernel<<<1, 128, 0, stream>>>(x,  cnt, ovf_cnt, ovf, x1);
    agg_kernel<<<agg_blocks, 256, 0, stream>>>(x1, cnt, bucket, out);
    ovf_fix_kernel<<<1, 128, 0, stream>>>(x1, cnt, ovf_cnt, ovf, out);
}

// Round 3
// 536.581 us; speedup vs baseline: 1.4092x; 1.0091x over previous
//
#include <hip/hip_runtime.h>
#include <hip/hip_fp16.h>
#include <math.h>

#define N_NODES 50000
#define N_EDGES 600000
#define D 128
#define EPS 1e-12f
#define CAP 64          // bucket slots per node; Poisson(12) => P(deg>64) ~ 1e-20,
                        // and the overflow path below keeps it correct regardless.

// ---------------- K0: convert fp32 x -> fp16 gather table -------------------
// Gathers are random-line-rate bound, not byte bound: fp16 rows are 256B =
// 4 cache lines instead of 8. Accumulation stays fp32; residual stays fp32.
__global__ void cvt_kernel(const float* __restrict__ x, ushort* __restrict__ xh) {
    int i = blockIdx.x * blockDim.x + threadIdx.x;   // one float4 / thread
    if (i >= N_NODES * D / 4) return;
    float4 v = ((const float4*)x)[i];
    ushort4 h;
    h.x = __half_as_ushort(__float2half(v.x));
    h.y = __half_as_ushort(__float2half(v.y));
    h.z = __half_as_ushort(__float2half(v.z));
    h.w = __half_as_ushort(__float2half(v.w));
    ((ushort4*)xh)[i] = h;
}

// ---------------- K1: fused edge cosine sim + bucket scatter ----------------
// two edges per wave: lanes 0-31 edge 2w, lanes 32-63 edge 2w+1, float4/lane.
// One atomic per edge claims a bucket slot; (src, sim) stored as int2.
__global__ void edge_fill_kernel(const float* __restrict__ ea,
                                 const float* __restrict__ q,
                                 const int* __restrict__ src,
                                 const int* __restrict__ dst,
                                 int* __restrict__ cnt,
                                 int2* __restrict__ bucket,
                                 int* __restrict__ ovf_cnt,
                                 int4* __restrict__ ovf) {
    int gid  = blockIdx.x * blockDim.x + threadIdx.x;
    int wave = gid >> 6;
    if (wave >= N_EDGES / 2) return;
    int lane = threadIdx.x & 63;
    int half = lane >> 5;
    int l32  = lane & 31;
    int e    = 2 * wave + half;

    float4 v  = ((const float4*)(ea + (size_t)e * D))[l32];
    float4 qv = ((const float4*)q)[l32];
    float dot = v.x * qv.x + v.y * qv.y + v.z * qv.z + v.w * qv.w;
    float ss  = v.x * v.x + v.y * v.y + v.z * v.z + v.w * v.w;
    float qs  = qv.x * qv.x + qv.y * qv.y + qv.z * qv.z + qv.w * qv.w;
    // reduce within each 32-lane half (xor offsets < 32 never cross halves)
    #pragma unroll
    for (int off = 16; off > 0; off >>= 1) {
        dot += __shfl_xor(dot, off);
        ss  += __shfl_xor(ss, off);
        qs  += __shfl_xor(qs, off);
    }
    if (l32 == 0) {
        float sim = dot / (fmaxf(sqrtf(ss), EPS) * fmaxf(sqrtf(qs), EPS));
        int d    = dst[e];
        int slot = atomicAdd(&cnt[d], 1);
        if (slot < CAP) {
            bucket[(size_t)d * CAP + slot] = make_int2(src[e], __float_as_int(sim));
        } else {
            int oi = atomicAdd(ovf_cnt, 1);
            ovf[oi] = make_int4(d, src[e], __float_as_int(sim), 0);
        }
    }
}

// ---------------- K2: fused gather-aggregate + mean + residual blend --------
// one wave per node. Bucket entries preloaded into lane registers, broadcast
// per-edge via shfl. Gather fp16 rows (256B = 4 lines) as ushort4 across 32
// lanes; the two wave halves process even/odd edges concurrently. fp32
// accumulate; fp32 residual from xin; writes fp32 xout and (optionally) the
// fp16 gather table for the next layer.
__global__ void agg_kernel(const ushort* __restrict__ xh,   // fp16 gather table
                           const float* __restrict__ xin,   // fp32 (residual)
                           const int* __restrict__ cnt,
                           const int2* __restrict__ bucket,
                           float* __restrict__ xout,        // fp32 out
                           ushort* __restrict__ xh_out) {   // fp16 out (nullable)
    int gid  = blockIdx.x * blockDim.x + threadIdx.x;
    int node = gid >> 6;
    if (node >= N_NODES) return;
    int lane = threadIdx.x & 63;
    int half = lane >> 5;
    int l32  = lane & 31;

    int n  = cnt[node];              // full degree (incl. any overflow edges)
    int nb = (n < CAP) ? n : CAP;    // edges present in the bucket

    // preload up to 64 (src, sim) pairs into registers - coalesced 512B
    int sl = 0; float wl = 0.0f;
    if (lane < nb) {
        int2 p = bucket[(size_t)node * CAP + lane];
        sl = p.x; wl = __int_as_float(p.y);
    }

    float4 acc = make_float4(0.0f, 0.0f, 0.0f, 0.0f);
    // halves interleave: half 0 takes even edges, half 1 odd
    #pragma unroll 2
    for (int j = half; j < nb; j += 2) {
        int   s = __shfl(sl, j);
        float w = __shfl(wl, j);
        ushort4 hv = ((const ushort4*)(xh + (size_t)s * D))[l32];  // 8B/lane
        acc.x += __half2float(__ushort_as_half(hv.x)) * w;
        acc.y += __half2float(__ushort_as_half(hv.y)) * w;
        acc.z += __half2float(__ushort_as_half(hv.z)) * w;
        acc.w += __half2float(__ushort_as_half(hv.w)) * w;
    }
    // combine the two halves
    acc.x += __shfl_xor(acc.x, 32);
    acc.y += __shfl_xor(acc.y, 32);
    acc.z += __shfl_xor(acc.z, 32);
    acc.w += __shfl_xor(acc.w, 32);

    if (half == 0) {
        float di = 1.0f / fmaxf((float)n, 1.0f);
        float4 a = ((const float4*)(xin + (size_t)node * D))[l32];
        float4 o;
        o.x = 0.5f * a.x + 0.5f * acc.x * di;
        o.y = 0.5f * a.y + 0.5f * acc.y * di;
        o.z = 0.5f * a.z + 0.5f * acc.z * di;
        o.w = 0.5f * a.w + 0.5f * acc.w * di;
        ((float4*)(xout + (size_t)node * D))[l32] = o;
        if (xh_out) {
            ushort4 h;
            h.x = __half_as_ushort(__float2half(o.x));
            h.y = __half_as_ushort(__float2half(o.y));
            h.z = __half_as_ushort(__float2half(o.z));
            h.w = __half_as_ushort(__float2half(o.w));
            ((ushort4*)(xh_out + (size_t)node * D))[l32] = h;
        }
    }
}

// ---------------- K3: overflow fixup (degree > CAP) — empty in practice -----
// Serial over overflow entries (no races); adds the missing 0.5*w*di*x[src]
// contribution into xout (fp32 gather - exact). Keeps the fp16 mirror in sync.
__global__ void ovf_fix_kernel(const float* __restrict__ xin,
                               const int* __restrict__ cnt,
                               const int* __restrict__ ovf_cnt,
                               const int4* __restrict__ ovf,
                               float* __restrict__ xout,
                               ushort* __restrict__ xh_out) {
    int t = threadIdx.x;             // 128 threads, 1 block
    int m = *ovf_cnt;
    for (int i = 0; i < m; ++i) {
        int4 p = ovf[i];
        int d = p.x, s = p.y;
        float w  = __int_as_float(p.z);
        float di = 1.0f / fmaxf((float)cnt[d], 1.0f);
        float r  = xout[(size_t)d * D + t] + 0.5f * w * di * xin[(size_t)s * D + t];
        xout[(size_t)d * D + t] = r;
        if (xh_out) xh_out[(size_t)d * D + t] = __half_as_ushort(__float2half(r));
    }
}

extern "C" void kernel_launch(void* const* d_in, const int* in_sizes, int n_in,
                              void* d_out, int out_size, void* d_ws, size_t ws_size,
                              hipStream_t stream) {
    const float* x  = (const float*)d_in[0];   // [N, D]
    const float* ea = (const float*)d_in[1];   // [E, D]
    const float* q  = (const float*)d_in[2];   // [D]
    const int*   ei = (const int*)d_in[3];     // [2, E]
    const int* src = ei;
    const int* dst = ei + N_EDGES;
    float* out = (float*)d_out;                // [N, D]

    // ---- workspace layout (16B-aligned pieces) ----
    float*  x1      = (float*)d_ws;                          // N*D f32 (25.6MB)
    ushort* xh      = (ushort*)(x1 + (size_t)N_NODES * D);   // N*D f16 (12.8MB)
    ushort* x1h     = xh + (size_t)N_NODES * D;              // N*D f16 (12.8MB)
    int2*   bucket  = (int2*)(x1h + (size_t)N_NODES * D);    // N*CAP int2 (25.6MB)
    int*    cnt     = (int*)(bucket + (size_t)N_NODES * CAP);// N ints
    int*    ovf_cnt = cnt + N_NODES;                         // 1 int (+3 pad)
    int4*   ovf     = (int4*)(cnt + N_NODES + 4);            // 64K entries max

    // zero cnt + ovf_cnt in one memset (contiguous)
    hipMemsetAsync(cnt, 0, (size_t)(N_NODES + 4) * sizeof(int), stream);

    cvt_kernel<<<(N_NODES * D / 4 + 255) / 256, 256, 0, stream>>>(x, xh);

    {   // one wave per 2 edges
        long long threads = (long long)(N_EDGES / 2) * 64;
        int blocks = (int)((threads + 255) / 256);
        edge_fill_kernel<<<blocks, 256, 0, stream>>>(ea, q, src, dst,
                                                     cnt, bucket, ovf_cnt, ovf);
    }

    const int agg_blocks = (int)(((long long)N_NODES * 64 + 255) / 256);
    // layer 1: gather xh, residual x  -> x1 (f32) + x1h (f16)
    agg_kernel<<<agg_blocks, 256, 0, stream>>>(xh,  x,  cnt, bucket, x1,  x1h);
    ovf_fix_kernel<<<1, 128, 0, stream>>>(x,  cnt, ovf_cnt, ovf, x1, x1h);
    // layer 2: gather x1h, residual x1 -> out (f32)
    agg_kernel<<<agg_blocks, 256, 0, stream>>>(x1h, x1, cnt, bucket, out, (ushort*)0);
    ovf_fix_kernel<<<1, 128, 0, stream>>>(x1, cnt, ovf_cnt, ovf, out, (ushort*)0);
}

// Round 4
// 521.716 us; speedup vs baseline: 1.4494x; 1.0285x over previous
//
#include <hip/hip_runtime.h>
#include <hip/hip_fp16.h>
#include <math.h>

#define N_NODES 50000
#define N_EDGES 600000
#define D 128
#define EPS 1e-12f
#define CAP 64          // bucket slots per node; Poisson(12) => P(deg>64) ~ 1e-20,
                        // and the overflow path below keeps it correct regardless.

// ---------------- K0: convert fp32 x -> fp16 gather table -------------------
__global__ void cvt_kernel(const float* __restrict__ x, ushort* __restrict__ xh) {
    int i = blockIdx.x * blockDim.x + threadIdx.x;   // one float4 / thread
    if (i >= N_NODES * D / 4) return;
    float4 v = ((const float4*)x)[i];
    ushort4 h;
    h.x = __half_as_ushort(__float2half(v.x));
    h.y = __half_as_ushort(__float2half(v.y));
    h.z = __half_as_ushort(__float2half(v.z));
    h.w = __half_as_ushort(__float2half(v.w));
    ((ushort4*)xh)[i] = h;
}

// ---------------- K1: fused edge cosine sim + bucket scatter ----------------
// (unchanged from round 3 for clean attribution)
__global__ void edge_fill_kernel(const float* __restrict__ ea,
                                 const float* __restrict__ q,
                                 const int* __restrict__ src,
                                 const int* __restrict__ dst,
                                 int* __restrict__ cnt,
                                 int2* __restrict__ bucket,
                                 int* __restrict__ ovf_cnt,
                                 int4* __restrict__ ovf) {
    int gid  = blockIdx.x * blockDim.x + threadIdx.x;
    int wave = gid >> 6;
    if (wave >= N_EDGES / 2) return;
    int lane = threadIdx.x & 63;
    int half = lane >> 5;
    int l32  = lane & 31;
    int e    = 2 * wave + half;

    float4 v  = ((const float4*)(ea + (size_t)e * D))[l32];
    float4 qv = ((const float4*)q)[l32];
    float dot = v.x * qv.x + v.y * qv.y + v.z * qv.z + v.w * qv.w;
    float ss  = v.x * v.x + v.y * v.y + v.z * v.z + v.w * v.w;
    float qs  = qv.x * qv.x + qv.y * qv.y + qv.z * qv.z + qv.w * qv.w;
    #pragma unroll
    for (int off = 16; off > 0; off >>= 1) {
        dot += __shfl_xor(dot, off);
        ss  += __shfl_xor(ss, off);
        qs  += __shfl_xor(qs, off);
    }
    if (l32 == 0) {
        float sim = dot / (fmaxf(sqrtf(ss), EPS) * fmaxf(sqrtf(qs), EPS));
        int d    = dst[e];
        int slot = atomicAdd(&cnt[d], 1);
        if (slot < CAP) {
            bucket[(size_t)d * CAP + slot] = make_int2(src[e], __float_as_int(sim));
        } else {
            int oi = atomicAdd(ovf_cnt, 1);
            ovf[oi] = make_int4(d, src[e], __float_as_int(sim), 0);
        }
    }
}

// ---------------- K2: high-MLP gather-aggregate -----------------------------
// One wave per node; lane owns dims {2*lane, 2*lane+1}. A full wave reads one
// fp16 row per load instruction (64 lanes x 4B = 256B). The up-to-16-edge
// batch precomputes all broadcast addresses, then issues 16 INDEPENDENT
// global loads back-to-back (no shfl/load dependency chain), then FMAs as
// they land. Lanes >= nb are padded (s=node, w=0) — branch-free. Second
// batch covers nb<=32 (~10% of nodes); generic tail beyond (~1e-6).
__global__ void agg_kernel(const ushort* __restrict__ xh,   // fp16 gather table
                           const float* __restrict__ xin,   // fp32 (residual)
                           const int* __restrict__ cnt,
                           const int2* __restrict__ bucket,
                           float* __restrict__ xout,        // fp32 out
                           ushort* __restrict__ xh_out) {   // fp16 out (nullable)
    int gid  = blockIdx.x * blockDim.x + threadIdx.x;
    int node = gid >> 6;
    if (node >= N_NODES) return;
    int lane = threadIdx.x & 63;

    int n  = cnt[node];              // full degree (incl. any overflow edges)
    int nb = (n < CAP) ? n : CAP;    // edges present in the bucket

    // preload up to 64 (src, sim) pairs into lane registers — one coalesced load
    int sl = node; float wl = 0.0f;  // padding: gather own row with weight 0
    if (lane < nb) {
        int2 p = bucket[(size_t)node * CAP + lane];
        sl = p.x; wl = __int_as_float(p.y);
    }

    const uint* base = (const uint*)xh;          // row = 64 uints (half2)
    float accx = 0.0f, accy = 0.0f;

    // ---- batch 0: edges 0..15, fully unrolled, 16 loads in flight ----
    uint off0[16];
    #pragma unroll
    for (int j = 0; j < 16; ++j) {
        int s = __shfl(sl, j);
        off0[j] = (uint)s * (D / 2) + lane;
    }
    uint u0[16];
    #pragma unroll
    for (int j = 0; j < 16; ++j) u0[j] = base[off0[j]];
    #pragma unroll
    for (int j = 0; j < 16; ++j) {
        float w = __shfl(wl, j);
        __half2 h2 = *reinterpret_cast<__half2*>(&u0[j]);
        float2 f = __half22float2(h2);
        accx += f.x * w; accy += f.y * w;
    }

    // ---- batch 1: edges 16..31 (wave-uniform branch, ~10% of nodes) ----
    if (nb > 16) {
        uint off1[16];
        #pragma unroll
        for (int j = 0; j < 16; ++j) {
            int s = __shfl(sl, 16 + j);
            off1[j] = (uint)s * (D / 2) + lane;
        }
        uint u1[16];
        #pragma unroll
        for (int j = 0; j < 16; ++j) u1[j] = base[off1[j]];
        #pragma unroll
        for (int j = 0; j < 16; ++j) {
            float w = __shfl(wl, 16 + j);
            __half2 h2 = *reinterpret_cast<__half2*>(&u1[j]);
            float2 f = __half22float2(h2);
            accx += f.x * w; accy += f.y * w;
        }
    }

    // ---- generic tail: nb in (32,64] — wave-uniform, effectively never ----
    for (int j = 32; j < nb; ++j) {
        int   s = __shfl(sl, j);
        float w = __shfl(wl, j);
        uint u = base[(uint)s * (D / 2) + lane];
        __half2 h2 = *reinterpret_cast<__half2*>(&u);
        float2 f = __half22float2(h2);
        accx += f.x * w; accy += f.y * w;
    }

    // ---- finalize: mean + residual blend, fp32 out (+ fp16 mirror) ----
    float di = 1.0f / fmaxf((float)n, 1.0f);
    float2 a = ((const float2*)xin)[(size_t)node * (D / 2) + lane];
    float2 o;
    o.x = 0.5f * a.x + 0.5f * accx * di;
    o.y = 0.5f * a.y + 0.5f * accy * di;
    ((float2*)xout)[(size_t)node * (D / 2) + lane] = o;
    if (xh_out) {
        __half2 hh = __floats2half2_rn(o.x, o.y);
        ((uint*)xh_out)[(size_t)node * (D / 2) + lane] = *reinterpret_cast<uint*>(&hh);
    }
}

// ---------------- K3: overflow fixup (degree > CAP) — empty in practice -----
__global__ void ovf_fix_kernel(const float* __restrict__ xin,
                               const int* __restrict__ cnt,
                               const int* __restrict__ ovf_cnt,
                               const int4* __restrict__ ovf,
                               float* __restrict__ xout,
                               ushort* __restrict__ xh_out) {
    int t = threadIdx.x;             // 128 threads, 1 block
    int m = *ovf_cnt;
    for (int i = 0; i < m; ++i) {
        int4 p = ovf[i];
        int d = p.x, s = p.y;
        float w  = __int_as_float(p.z);
        float di = 1.0f / fmaxf((float)cnt[d], 1.0f);
        float r  = xout[(size_t)d * D + t] + 0.5f * w * di * xin[(size_t)s * D + t];
        xout[(size_t)d * D + t] = r;
        if (xh_out) xh_out[(size_t)d * D + t] = __half_as_ushort(__float2half(r));
    }
}

extern "C" void kernel_launch(void* const* d_in, const int* in_sizes, int n_in,
                              void* d_out, int out_size, void* d_ws, size_t ws_size,
                              hipStream_t stream) {
    const float* x  = (const float*)d_in[0];   // [N, D]
    const float* ea = (const float*)d_in[1];   // [E, D]
    const float* q  = (const float*)d_in[2];   // [D]
    const int*   ei = (const int*)d_in[3];     // [2, E]
    const int* src = ei;
    const int* dst = ei + N_EDGES;
    float* out = (float*)d_out;                // [N, D]

    // ---- workspace layout (16B-aligned pieces) ----
    float*  x1      = (float*)d_ws;                          // N*D f32 (25.6MB)
    ushort* xh      = (ushort*)(x1 + (size_t)N_NODES * D);   // N*D f16 (12.8MB)
    ushort* x1h     = xh + (size_t)N_NODES * D;              // N*D f16 (12.8MB)
    int2*   bucket  = (int2*)(x1h + (size_t)N_NODES * D);    // N*CAP int2 (25.6MB)
    int*    cnt     = (int*)(bucket + (size_t)N_NODES * CAP);// N ints
    int*    ovf_cnt = cnt + N_NODES;                         // 1 int (+3 pad)
    int4*   ovf     = (int4*)(cnt + N_NODES + 4);            // 64K entries max

    hipMemsetAsync(cnt, 0, (size_t)(N_NODES + 4) * sizeof(int), stream);

    cvt_kernel<<<(N_NODES * D / 4 + 255) / 256, 256, 0, stream>>>(x, xh);

    {   // one wave per 2 edges
        long long threads = (long long)(N_EDGES / 2) * 64;
        int blocks = (int)((threads + 255) / 256);
        edge_fill_kernel<<<blocks, 256, 0, stream>>>(ea, q, src, dst,
                                                     cnt, bucket, ovf_cnt, ovf);
    }

    const int agg_blocks = (int)(((long long)N_NODES * 64 + 255) / 256);
    // layer 1: gather xh, residual x  -> x1 (f32) + x1h (f16)
    agg_kernel<<<agg_blocks, 256, 0, stream>>>(xh,  x,  cnt, bucket, x1,  x1h);
    ovf_fix_kernel<<<1, 128, 0, stream>>>(x,  cnt, ovf_cnt, ovf, x1, x1h);
    // layer 2: gather x1h, residual x1 -> out (f32)
    agg_kernel<<<agg_blocks, 256, 0, stream>>>(x1h, x1, cnt, bucket, out, (ushort*)0);
    ovf_fix_kernel<<<1, 128, 0, stream>>>(x1, cnt, ovf_cnt, ovf, out, (ushort*)0);
}

// Round 5
// 519.009 us; speedup vs baseline: 1.4569x; 1.0052x over previous
//
#include <hip/hip_runtime.h>
#include <hip/hip_fp16.h>
#include <math.h>

#define N_NODES 50000
#define N_EDGES 600000
#define D 128
#define EPS 1e-12f
#define CAP 64          // bucket slots per node; Poisson(12) => P(deg>64) ~ 1e-20,
                        // and the inline overflow path keeps it correct regardless.

typedef float f32x4 __attribute__((ext_vector_type(4)));

// ---------------- K0: prep = zero cnt/ovf_cnt + cvt fp32 x -> fp16 ----------
__global__ void prep_kernel(const float* __restrict__ x, ushort* __restrict__ xh,
                            int* __restrict__ cnt) {
    int i = blockIdx.x * blockDim.x + threadIdx.x;
    if (i < N_NODES + 4) cnt[i] = 0;                 // cnt + ovf_cnt (+pad)
    if (i < N_NODES * D / 4) {
        float4 v = ((const float4*)x)[i];
        ushort4 h;
        h.x = __half_as_ushort(__float2half(v.x));
        h.y = __half_as_ushort(__float2half(v.y));
        h.z = __half_as_ushort(__float2half(v.z));
        h.w = __half_as_ushort(__float2half(v.w));
        ((ushort4*)xh)[i] = h;
    }
}

// ---------------- K1: fused edge cosine sim + bucket scatter ----------------
// two edges per wave; ea streamed with non-temporal loads (read-once 307MB,
// keep L2 for cnt/bucket lines).
__global__ void edge_fill_kernel(const float* __restrict__ ea,
                                 const float* __restrict__ q,
                                 const int* __restrict__ src,
                                 const int* __restrict__ dst,
                                 int* __restrict__ cnt,
                                 int2* __restrict__ bucket,
                                 int* __restrict__ ovf_cnt,
                                 int4* __restrict__ ovf) {
    int gid  = blockIdx.x * blockDim.x + threadIdx.x;
    int wave = gid >> 6;
    if (wave >= N_EDGES / 2) return;
    int lane = threadIdx.x & 63;
    int half = lane >> 5;
    int l32  = lane & 31;
    int e    = 2 * wave + half;

    f32x4 v  = __builtin_nontemporal_load(((const f32x4*)(ea + (size_t)e * D)) + l32);
    float4 qv = ((const float4*)q)[l32];
    float dot = v.x * qv.x + v.y * qv.y + v.z * qv.z + v.w * qv.w;
    float ss  = v.x * v.x + v.y * v.y + v.z * v.z + v.w * v.w;
    float qs  = qv.x * qv.x + qv.y * qv.y + qv.z * qv.z + qv.w * qv.w;
    #pragma unroll
    for (int off = 16; off > 0; off >>= 1) {
        dot += __shfl_xor(dot, off);
        ss  += __shfl_xor(ss, off);
        qs  += __shfl_xor(qs, off);
    }
    if (l32 == 0) {
        float sim = dot / (fmaxf(sqrtf(ss), EPS) * fmaxf(sqrtf(qs), EPS));
        int d    = dst[e];
        int slot = atomicAdd(&cnt[d], 1);
        if (slot < CAP) {
            bucket[(size_t)d * CAP + slot] = make_int2(src[e], __float_as_int(sim));
        } else {
            int oi = atomicAdd(ovf_cnt, 1);
            ovf[oi] = make_int4(d, src[e], __float_as_int(sim), 0);
        }
    }
}

// unpack 8 fp16 (as uint4) and accumulate with weight w — all-static names
__device__ __forceinline__ void acc8(uint4 v, float w,
                                     float& a0, float& a1, float& a2, float& a3,
                                     float& a4, float& a5, float& a6, float& a7) {
    float2 f;
    f = __half22float2(*reinterpret_cast<const __half2*>(&v.x)); a0 += f.x * w; a1 += f.y * w;
    f = __half22float2(*reinterpret_cast<const __half2*>(&v.y)); a2 += f.x * w; a3 += f.y * w;
    f = __half22float2(*reinterpret_cast<const __half2*>(&v.z)); a4 += f.x * w; a5 += f.y * w;
    f = __half22float2(*reinterpret_cast<const __half2*>(&v.w)); a6 += f.x * w; a7 += f.y * w;
}

// ---------------- K2: group-gather aggregate --------------------------------
// One wave per node. Four 16-lane groups; group g handles edge 4*js+g and
// reads a FULL fp16 row per load instruction (16 lanes x 16B = 256B). 4 edges
// per instruction, 16 edges in flight in batch 0. Padding lanes re-gather the
// first edge's row (L1-hot => ~free) with weight 0. Overflow (deg>CAP) is
// handled inline by scanning the ovf list (ovf_cnt==0 always in practice).
__global__ void agg_kernel(const ushort* __restrict__ xh,   // fp16 gather table
                           const float* __restrict__ xin,   // fp32 (residual)
                           const int* __restrict__ cnt,
                           const int2* __restrict__ bucket,
                           const int* __restrict__ ovf_cnt,
                           const int4* __restrict__ ovf,
                           float* __restrict__ xout,        // fp32 out
                           ushort* __restrict__ xh_out) {   // fp16 out (nullable)
    int gid  = blockIdx.x * blockDim.x + threadIdx.x;
    int node = gid >> 6;
    if (node >= N_NODES) return;
    int lane = threadIdx.x & 63;
    int g    = lane >> 4;         // edge slot within a 4-edge step
    int l16  = lane & 15;

    int n  = cnt[node];
    int nb = (n < CAP) ? n : CAP;

    // preload (src, sim) pairs; pad lanes with (first-src, 0) => L1-hot pads
    int sl = node; float wl = 0.0f;
    if (lane < nb) {
        int2 p = bucket[(size_t)node * CAP + lane];
        sl = p.x; wl = __int_as_float(p.y);
    }
    int s0 = __shfl(sl, 0);
    if (lane >= nb) sl = s0;

    const uint4* base = (const uint4*)xh;        // fp16 row = 16 x uint4
    float a0 = 0, a1 = 0, a2 = 0, a3 = 0, a4 = 0, a5 = 0, a6 = 0, a7 = 0;

    // ---- batch 0: edges 0..15 (4 steps x 4 groups), unconditional ----
    {
        int   e0 = g,      e1 = 4 + g,  e2 = 8 + g,  e3 = 12 + g;
        int   s_0 = __shfl(sl, e0), s_1 = __shfl(sl, e1), s_2 = __shfl(sl, e2), s_3 = __shfl(sl, e3);
        float w_0 = __shfl(wl, e0), w_1 = __shfl(wl, e1), w_2 = __shfl(wl, e2), w_3 = __shfl(wl, e3);
        uint4 v_0 = base[(size_t)s_0 * 16 + l16];
        uint4 v_1 = base[(size_t)s_1 * 16 + l16];
        uint4 v_2 = base[(size_t)s_2 * 16 + l16];
        uint4 v_3 = base[(size_t)s_3 * 16 + l16];
        acc8(v_0, w_0, a0, a1, a2, a3, a4, a5, a6, a7);
        acc8(v_1, w_1, a0, a1, a2, a3, a4, a5, a6, a7);
        acc8(v_2, w_2, a0, a1, a2, a3, a4, a5, a6, a7);
        acc8(v_3, w_3, a0, a1, a2, a3, a4, a5, a6, a7);
    }
    // ---- batch 1: edges 16..31 (wave-uniform, ~10% of nodes) ----
    if (nb > 16) {
        int   e0 = 16 + g, e1 = 20 + g, e2 = 24 + g, e3 = 28 + g;
        int   s_0 = __shfl(sl, e0), s_1 = __shfl(sl, e1), s_2 = __shfl(sl, e2), s_3 = __shfl(sl, e3);
        float w_0 = __shfl(wl, e0), w_1 = __shfl(wl, e1), w_2 = __shfl(wl, e2), w_3 = __shfl(wl, e3);
        uint4 v_0 = base[(size_t)s_0 * 16 + l16];
        uint4 v_1 = base[(size_t)s_1 * 16 + l16];
        uint4 v_2 = base[(size_t)s_2 * 16 + l16];
        uint4 v_3 = base[(size_t)s_3 * 16 + l16];
        acc8(v_0, w_0, a0, a1, a2, a3, a4, a5, a6, a7);
        acc8(v_1, w_1, a0, a1, a2, a3, a4, a5, a6, a7);
        acc8(v_2, w_2, a0, a1, a2, a3, a4, a5, a6, a7);
        acc8(v_3, w_3, a0, a1, a2, a3, a4, a5, a6, a7);
    }
    // ---- tail: edges 32..63 (effectively never) ----
    for (int js = 8; 4 * js < nb; ++js) {
        int   e0 = 4 * js + g;
        int   s_0 = __shfl(sl, e0);
        float w_0 = __shfl(wl, e0);
        uint4 v_0 = base[(size_t)s_0 * 16 + l16];
        acc8(v_0, w_0, a0, a1, a2, a3, a4, a5, a6, a7);
    }

    // ---- combine groups: lanes {l, l^16, l^32, l^48} hold same dims ----
    #define RED(A) A += __shfl_xor(A, 16); A += __shfl_xor(A, 32);
    RED(a0) RED(a1) RED(a2) RED(a3) RED(a4) RED(a5) RED(a6) RED(a7)
    #undef RED

    // ---- inline overflow fixup (deg > CAP): m == 0 in practice ----
    int m = *ovf_cnt;
    if (m > 0) {
        for (int i = 0; i < m; ++i) {
            int4 p = ovf[i];
            if (p.x == node) {
                float w = __int_as_float(p.z);
                const float* r = xin + (size_t)p.y * D + l16 * 8;
                a0 += w * r[0]; a1 += w * r[1]; a2 += w * r[2]; a3 += w * r[3];
                a4 += w * r[4]; a5 += w * r[5]; a6 += w * r[6]; a7 += w * r[7];
            }
        }
    }

    // ---- finalize: mean + residual blend; groups 0,1 write 512B row ----
    if (g < 2) {
        float di = 1.0f / fmaxf((float)n, 1.0f);
        size_t idx = (size_t)node * 32 + l16 * 2 + g;   // float4 units
        float4 a = ((const float4*)xin)[idx];
        float4 o;
        if (g == 0) {
            o.x = 0.5f * a.x + 0.5f * a0 * di;
            o.y = 0.5f * a.y + 0.5f * a1 * di;
            o.z = 0.5f * a.z + 0.5f * a2 * di;
            o.w = 0.5f * a.w + 0.5f * a3 * di;
        } else {
            o.x = 0.5f * a.x + 0.5f * a4 * di;
            o.y = 0.5f * a.y + 0.5f * a5 * di;
            o.z = 0.5f * a.z + 0.5f * a6 * di;
            o.w = 0.5f * a.w + 0.5f * a7 * di;
        }
        ((float4*)xout)[idx] = o;
        if (xh_out) {
            __half2 h0 = __floats2half2_rn(o.x, o.y);
            __half2 h1 = __floats2half2_rn(o.z, o.w);
            uint2 u;
            u.x = *reinterpret_cast<uint*>(&h0);
            u.y = *reinterpret_cast<uint*>(&h1);
            ((uint2*)xh_out)[idx] = u;
        }
    }
}

extern "C" void kernel_launch(void* const* d_in, const int* in_sizes, int n_in,
                              void* d_out, int out_size, void* d_ws, size_t ws_size,
                              hipStream_t stream) {
    const float* x  = (const float*)d_in[0];   // [N, D]
    const float* ea = (const float*)d_in[1];   // [E, D]
    const float* q  = (const float*)d_in[2];   // [D]
    const int*   ei = (const int*)d_in[3];     // [2, E]
    const int* src = ei;
    const int* dst = ei + N_EDGES;
    float* out = (float*)d_out;                // [N, D]

    // ---- workspace layout (16B-aligned pieces) ----
    float*  x1      = (float*)d_ws;                          // N*D f32 (25.6MB)
    ushort* xh      = (ushort*)(x1 + (size_t)N_NODES * D);   // N*D f16 (12.8MB)
    ushort* x1h     = xh + (size_t)N_NODES * D;              // N*D f16 (12.8MB)
    int2*   bucket  = (int2*)(x1h + (size_t)N_NODES * D);    // N*CAP int2 (25.6MB)
    int*    cnt     = (int*)(bucket + (size_t)N_NODES * CAP);// N ints
    int*    ovf_cnt = cnt + N_NODES;                         // 1 int (+3 pad)
    int4*   ovf     = (int4*)(cnt + N_NODES + 4);            // 64K entries max

    // prep: zero cnt/ovf_cnt + build fp16 gather table (replaces memset+cvt)
    prep_kernel<<<(N_NODES * D / 4 + 255) / 256, 256, 0, stream>>>(x, xh, cnt);

    {   // one wave per 2 edges
        long long threads = (long long)(N_EDGES / 2) * 64;
        int blocks = (int)((threads + 255) / 256);
        edge_fill_kernel<<<blocks, 256, 0, stream>>>(ea, q, src, dst,
                                                     cnt, bucket, ovf_cnt, ovf);
    }

    const int agg_blocks = (int)(((long long)N_NODES * 64 + 255) / 256);
    // layer 1: gather xh, residual x  -> x1 (f32) + x1h (f16)
    agg_kernel<<<agg_blocks, 256, 0, stream>>>(xh,  x,  cnt, bucket, ovf_cnt, ovf, x1,  x1h);
    // layer 2: gather x1h, residual x1 -> out (f32)
    agg_kernel<<<agg_blocks, 256, 0, stream>>>(x1h, x1, cnt, bucket, ovf_cnt, ovf, out, (ushort*)0);
}